// Round 7
// baseline (3562.499 us; speedup 1.0000x reference)
//
#include <hip/hip_runtime.h>
#include <stdint.h>

// Problem constants: B=64, T=512, I=256, H=512, L=2
#define Bn 64
#define Tn 512
#define In 256
#define Hn 512
#define NBLK 64                    // 32 blocks layer0 + 32 blocks layer1
#define OUT_HT 16777216            // B*T*H  (start of hT)
#define OUT_CT 16842752            // OUT_HT + 2*B*H (start of cT)
#define LDS_BYTES 131072           // layer1: 64KB wx1-frags + 64KB wh1-frags
#define SLOT_ELEMS (Bn * Hn)       // 32768 bf16 = 64KB per h slot
#define DONE_WORDS (2 * 4 * Tn * 32)   // done[layer][wv][t][cb] (flags mode)
#define DONE_BYTES (DONE_WORDS * 4)
#define NSLOT_CAN (Tn + 1)         // canary mode: no slot reuse, 513 slots
#define MAX_RETRY (1 << 20)        // bounded spin: deadlock -> visible failure

// ---------------------------------------------------------------------------
// v7 = v6 (zero-flag NaN-canary dataflow) hardened:
//  * canary detection is INTEGER now: e = dword ^ 0x7FC17FC1; v_pk_min_u16
//    accumulate; zero halfword in min <=> canary seen. Immune to fast-math
//    (old float x*0 trick could constant-fold), ~2x cheaper.
//  * all retry spins bounded (MAX_RETRY) -> a visibility bug produces a
//    wrong answer, not a container-killing hang.
//  * Canary mode (ws >= ~68MB): rings have 513 slots, each written ONCE.
//    prep fills with bf16 NaN 0x7FC1 (slot 0 = zeros = h(-1)). A consumer
//    load validates itself -> per-step store-drain, publish, and flag-poll
//    L3 round-trips all eliminated. Producers never wait -> acyclic.
//  * Flags mode = v5 verbatim fallback (best known flag-based kernel).
// ---------------------------------------------------------------------------

typedef __attribute__((ext_vector_type(8))) short bf16x8;
typedef __attribute__((ext_vector_type(4))) float f32x4;
typedef unsigned long long u64;

__device__ __forceinline__ unsigned short f2bf(float f) {   // fp32 -> bf16 RNE
    unsigned u = __float_as_uint(f);
    return (unsigned short)((u + 0x7fffu + ((u >> 16) & 1u)) >> 16);
}
__device__ __forceinline__ float sigm(float v) { return 1.0f / (1.0f + __expf(-v)); }
__device__ __forceinline__ float tanhv(float v) { float e = __expf(2.0f * v); return 1.0f - 2.0f / (e + 1.0f); }

// sc0/sc1 accesses: bypass per-XCD L1/L2, coherent at Infinity Cache (L3).
__device__ __forceinline__ void stg_coh(unsigned short* p, unsigned short v) {
    __hip_atomic_store(p, v, __ATOMIC_RELAXED, __HIP_MEMORY_SCOPE_AGENT);
}
__device__ __forceinline__ int ld_cnt(const int* p) {
    return __hip_atomic_load(p, __ATOMIC_RELAXED, __HIP_MEMORY_SCOPE_AGENT);
}
__device__ __forceinline__ void st_flag(int* p, int v) {
    __hip_atomic_store(p, v, __ATOMIC_RELAXED, __HIP_MEMORY_SCOPE_AGENT);
}
__device__ __forceinline__ bf16x8 asbf(f32x4 v) {
    union { f32x4 f; bf16x8 h; } u; u.f = v; return u.h;
}
__device__ __forceinline__ unsigned pkminu16(unsigned a, unsigned b) {
    unsigned d;
    asm("v_pk_min_u16 %0, %1, %2" : "=v"(d) : "v"(a), "v"(b));
    return d;
}

// Issue 16 batched sc1 frag loads (h rings), NO trailing waitcnt.
#define GLD16_ISSUE(A, VA)                                             \
  asm volatile(                                                        \
    "global_load_dwordx4 %0,  %16, off offset:0 sc0 sc1\n\t"          \
    "global_load_dwordx4 %1,  %16, off offset:64 sc0 sc1\n\t"         \
    "global_load_dwordx4 %2,  %16, off offset:128 sc0 sc1\n\t"        \
    "global_load_dwordx4 %3,  %16, off offset:192 sc0 sc1\n\t"        \
    "global_load_dwordx4 %4,  %16, off offset:256 sc0 sc1\n\t"        \
    "global_load_dwordx4 %5,  %16, off offset:320 sc0 sc1\n\t"        \
    "global_load_dwordx4 %6,  %16, off offset:384 sc0 sc1\n\t"        \
    "global_load_dwordx4 %7,  %16, off offset:448 sc0 sc1\n\t"        \
    "global_load_dwordx4 %8,  %16, off offset:512 sc0 sc1\n\t"        \
    "global_load_dwordx4 %9,  %16, off offset:576 sc0 sc1\n\t"        \
    "global_load_dwordx4 %10, %16, off offset:640 sc0 sc1\n\t"        \
    "global_load_dwordx4 %11, %16, off offset:704 sc0 sc1\n\t"        \
    "global_load_dwordx4 %12, %16, off offset:768 sc0 sc1\n\t"        \
    "global_load_dwordx4 %13, %16, off offset:832 sc0 sc1\n\t"        \
    "global_load_dwordx4 %14, %16, off offset:896 sc0 sc1\n\t"        \
    "global_load_dwordx4 %15, %16, off offset:960 sc0 sc1"             \
    : "=&v"(A[0]), "=&v"(A[1]), "=&v"(A[2]), "=&v"(A[3]),              \
      "=&v"(A[4]), "=&v"(A[5]), "=&v"(A[6]), "=&v"(A[7]),              \
      "=&v"(A[8]), "=&v"(A[9]), "=&v"(A[10]), "=&v"(A[11]),            \
      "=&v"(A[12]), "=&v"(A[13]), "=&v"(A[14]), "=&v"(A[15])           \
    : "v"(VA) : "memory")

// x(t) loads (read-only input, normal cached path), row-pair offset pattern.
#define GLD16X(A, VA)                                                  \
  asm volatile(                                                        \
    "global_load_dwordx4 %0,  %16, off offset:0\n\t"                   \
    "global_load_dwordx4 %1,  %16, off offset:16\n\t"                  \
    "global_load_dwordx4 %2,  %16, off offset:128\n\t"                 \
    "global_load_dwordx4 %3,  %16, off offset:144\n\t"                 \
    "global_load_dwordx4 %4,  %16, off offset:256\n\t"                 \
    "global_load_dwordx4 %5,  %16, off offset:272\n\t"                 \
    "global_load_dwordx4 %6,  %16, off offset:384\n\t"                 \
    "global_load_dwordx4 %7,  %16, off offset:400\n\t"                 \
    "global_load_dwordx4 %8,  %16, off offset:512\n\t"                 \
    "global_load_dwordx4 %9,  %16, off offset:528\n\t"                 \
    "global_load_dwordx4 %10, %16, off offset:640\n\t"                 \
    "global_load_dwordx4 %11, %16, off offset:656\n\t"                 \
    "global_load_dwordx4 %12, %16, off offset:768\n\t"                 \
    "global_load_dwordx4 %13, %16, off offset:784\n\t"                 \
    "global_load_dwordx4 %14, %16, off offset:896\n\t"                 \
    "global_load_dwordx4 %15, %16, off offset:912"                     \
    : "=&v"(A[0]), "=&v"(A[1]), "=&v"(A[2]), "=&v"(A[3]),              \
      "=&v"(A[4]), "=&v"(A[5]), "=&v"(A[6]), "=&v"(A[7]),              \
      "=&v"(A[8]), "=&v"(A[9]), "=&v"(A[10]), "=&v"(A[11]),            \
      "=&v"(A[12]), "=&v"(A[13]), "=&v"(A[14]), "=&v"(A[15])           \
    : "v"(VA) : "memory")

// Counted wait + scheduling fence (rule #18: nothing crosses the barrier).
#define VMW(n) do {                                                    \
    asm volatile("s_waitcnt vmcnt(" #n ")" ::: "memory");              \
    __builtin_amdgcn_sched_barrier(0);                                 \
  } while (0)

// Integer canary scan over 16 f32x4 (64 dwords = 128 bf16): XOR with the
// canary pattern, pk_min_u16-accumulate; a zero halfword <=> canary present.
// Real h is finite (|h|<1) so bf16 0x7FC1 (NaN) cannot occur in real data.
#define CANCHK(A, OK) do {                                             \
    unsigned m0_ = 0xFFFFFFFFu, m1_ = 0xFFFFFFFFu,                     \
             m2_ = 0xFFFFFFFFu, m3_ = 0xFFFFFFFFu;                     \
    _Pragma("unroll")                                                  \
    for (int i_ = 0; i_ < 16; ++i_) {                                  \
      m0_ = pkminu16(m0_, __float_as_uint(A[i_][0]) ^ 0x7FC17FC1u);    \
      m1_ = pkminu16(m1_, __float_as_uint(A[i_][1]) ^ 0x7FC17FC1u);    \
      m2_ = pkminu16(m2_, __float_as_uint(A[i_][2]) ^ 0x7FC17FC1u);    \
      m3_ = pkminu16(m3_, __float_as_uint(A[i_][3]) ^ 0x7FC17FC1u);    \
    }                                                                  \
    unsigned mt_ = pkminu16(pkminu16(m0_, m1_), pkminu16(m2_, m3_));   \
    OK = __all(((mt_ & 0xFFFFu) != 0u) && ((mt_ >> 16) != 0u));        \
  } while (0)

__global__ void lstm_prep(u64* __restrict__ z0, u64* __restrict__ z1,
                          int* __restrict__ dn, int mode) {
    long tid = (long)blockIdx.x * blockDim.x + threadIdx.x;
    long stride = (long)gridDim.x * blockDim.x;
    if (mode == 0) {
        for (long i = tid; i < DONE_WORDS; i += stride) st_flag(dn + i, 0);
        for (long i = tid; i < SLOT_ELEMS / 4; i += stride) {
            __hip_atomic_store(z0 + i, (u64)0, __ATOMIC_RELAXED, __HIP_MEMORY_SCOPE_AGENT);
            __hip_atomic_store(z1 + i, (u64)0, __ATOMIC_RELAXED, __HIP_MEMORY_SCOPE_AGENT);
        }
    } else {
        const u64 CAN = 0x7FC17FC17FC17FC1ull;
        const long N = (long)NSLOT_CAN * (SLOT_ELEMS / 4);   // u64 per ring
        for (long i = tid; i < N; i += stride) {
            u64 v = (i < SLOT_ELEMS / 4) ? 0ull : CAN;       // slot 0 = h(-1)=0
            __hip_atomic_store(z0 + i, v, __ATOMIC_RELAXED, __HIP_MEMORY_SCOPE_AGENT);
            __hip_atomic_store(z1 + i, v, __ATOMIC_RELAXED, __HIP_MEMORY_SCOPE_AGENT);
        }
    }
}

// ---- shared weight-staging preamble (identical for both kernels) ----
#define STAGE_WEIGHTS()                                                      \
    const int I0 = (layer == 0) ? 8 : 16;                                    \
    const int K0 = (layer == 0) ? In : Hn;                                   \
    const float* Wxs = (layer == 0) ? wxh0 : wxh1;                           \
    const float* Whs = (layer == 0) ? whh0 : whh1;                           \
    u64* sm64 = (u64*)smem;                                                  \
    const int tot0 = I0 * 4 * 64;                                            \
    for (int c = threadIdx.x; c < tot0; c += 256) {                          \
        int lc = c & 63, qg = (c >> 6) & 3, ii = c >> 8;                     \
        const float* src = Wxs + (size_t)(qg * Hn + (cb << 4) + (lc & 15)) * K0 \
                               + ii * 32 + (lc >> 4) * 8;                    \
        f32x4 s0 = *(const f32x4*)src;                                       \
        f32x4 s1 = *(const f32x4*)(src + 4);                                 \
        u64 lo = (u64)f2bf(s0[0]) | ((u64)f2bf(s0[1]) << 16) |               \
                 ((u64)f2bf(s0[2]) << 32) | ((u64)f2bf(s0[3]) << 48);        \
        u64 hi = (u64)f2bf(s1[0]) | ((u64)f2bf(s1[1]) << 16) |               \
                 ((u64)f2bf(s1[2]) << 32) | ((u64)f2bf(s1[3]) << 48);        \
        sm64[c * 2] = lo; sm64[c * 2 + 1] = hi;                              \
    }                                                                        \
    const int hbase = tot0;                                                  \
    for (int c = threadIdx.x; c < 16 * 4 * 64; c += 256) {                   \
        int lc = c & 63, qg = (c >> 6) & 3, ii = c >> 8;                     \
        const float* src = Whs + (size_t)(qg * Hn + (cb << 4) + (lc & 15)) * Hn \
                               + ii * 32 + (lc >> 4) * 8;                    \
        f32x4 s0 = *(const f32x4*)src;                                       \
        f32x4 s1 = *(const f32x4*)(src + 4);                                 \
        u64 lo = (u64)f2bf(s0[0]) | ((u64)f2bf(s0[1]) << 16) |               \
                 ((u64)f2bf(s0[2]) << 32) | ((u64)f2bf(s0[3]) << 48);        \
        u64 hi = (u64)f2bf(s1[0]) | ((u64)f2bf(s1[1]) << 16) |               \
                 ((u64)f2bf(s1[2]) << 32) | ((u64)f2bf(s1[3]) << 48);        \
        sm64[(hbase + c) * 2] = lo; sm64[(hbase + c) * 2 + 1] = hi;          \
    }                                                                        \
    __syncthreads();                                                         \
    const bf16x8* bfr = (const bf16x8*)smem;

// =================== canary-mode kernel (zero flags) ===================
__launch_bounds__(256, 1)
__global__ void lstm_canary(const float* __restrict__ x,
                            const float* __restrict__ wxh0, const float* __restrict__ whh0,
                            const float* __restrict__ wxh1, const float* __restrict__ whh1,
                            const float* __restrict__ bx0, const float* __restrict__ bh0,
                            const float* __restrict__ bx1, const float* __restrict__ bh1,
                            float* __restrict__ out,
                            unsigned short* __restrict__ h0b,
                            unsigned short* __restrict__ h1b) {
    extern __shared__ char smem[];
    const int layer = blockIdx.x >> 5;
    const int cb    = blockIdx.x & 31;
    const int wv    = threadIdx.x >> 6;
    const int lane  = threadIdx.x & 63;
    const int quad  = lane >> 4;
    const int ln    = lane & 15;
    const int row0  = wv << 4;
    const int colh  = (cb << 4) + ln;

    STAGE_WEIGHTS();

    float bias[4];
#pragma unroll
    for (int q = 0; q < 4; ++q) {
        int gc = q * Hn + colh;
        bias[q] = (layer == 0) ? (bx0[gc] + bh0[gc]) : (bx1[gc] + bh1[gc]);
    }

    const float* xrow0 = x + (size_t)(row0 + ln) * Tn * In + quad * 8;
    const int hoff = (row0 + ln) * Hn + quad * 8;

    float c[4] = {0.f, 0.f, 0.f, 0.f};

    for (int t = 0; t < Tn; ++t) {
        f32x4 acc[4];
#pragma unroll
        for (int q = 0; q < 4; ++q) acc[q] = (f32x4){bias[q], bias[q], bias[q], bias[q]};

        if (layer == 0) {
            // h0(t-1) at slot t (written once; canary until producer stores)
            const unsigned short* hp = h0b + (size_t)t * SLOT_ELEMS + hoff;
            uint64_t va = (uint64_t)hp;
            f32x4 A[16], xr[16];
            uint64_t vax = (uint64_t)(xrow0 + (size_t)t * In);
            GLD16_ISSUE(A, va);        // oldest batch
            GLD16X(xr, vax);           // younger: x(t), cached path
            VMW(16);                   // drains prev-step stores + A; x flies
            int ok; CANCHK(A, ok);
            int tries = 0;
            while (!ok && ++tries < MAX_RETRY) {
                GLD16_ISSUE(A, va); VMW(0); CANCHK(A, ok);
            }
            // h-part MFMAs (x loads still in flight underneath)
#pragma unroll
            for (int i = 0; i < 16; ++i)
#pragma unroll
                for (int q = 0; q < 4; ++q)
                    acc[q] = __builtin_amdgcn_mfma_f32_16x16x32_bf16(
                        asbf(A[i]), bfr[hbase + (i * 4 + q) * 64 + lane], acc[q], 0, 0, 0);
            VMW(0);                    // x arrived
            bf16x8 axc[8];
#pragma unroll
            for (int i = 0; i < 8; ++i) {
                f32x4 xa = xr[2 * i], xc = xr[2 * i + 1];
                axc[i][0] = (short)f2bf(xa[0]); axc[i][1] = (short)f2bf(xa[1]);
                axc[i][2] = (short)f2bf(xa[2]); axc[i][3] = (short)f2bf(xa[3]);
                axc[i][4] = (short)f2bf(xc[0]); axc[i][5] = (short)f2bf(xc[1]);
                axc[i][6] = (short)f2bf(xc[2]); axc[i][7] = (short)f2bf(xc[3]);
            }
#pragma unroll
            for (int i = 0; i < 8; ++i)
#pragma unroll
                for (int q = 0; q < 4; ++q)
                    acc[q] = __builtin_amdgcn_mfma_f32_16x16x32_bf16(
                        axc[i], bfr[(i * 4 + q) * 64 + lane], acc[q], 0, 0, 0);
        } else {
            // h0(t) at h0 slot t+1 (likely ready: L0 runs ahead, never waits);
            // h1(t-1) at h1 slot t (the pacing load).
            const unsigned short* p0 = h0b + (size_t)(t + 1) * SLOT_ELEMS + hoff;
            const unsigned short* p1 = h1b + (size_t)t * SLOT_ELEMS + hoff;
            uint64_t va = (uint64_t)p0, vb = (uint64_t)p1;
            f32x4 A[16], Bv[16];
            GLD16_ISSUE(A, va);
            GLD16_ISSUE(Bv, vb);
            VMW(16);                   // drains prev stores + A; B flies
            int ok; CANCHK(A, ok);
            int tries = 0;
            while (!ok && ++tries < MAX_RETRY) {
                GLD16_ISSUE(A, va); VMW(0); CANCHK(A, ok);
            }
            // h0 MFMAs overlap B's flight
#pragma unroll
            for (int i = 0; i < 16; ++i)
#pragma unroll
                for (int q = 0; q < 4; ++q)
                    acc[q] = __builtin_amdgcn_mfma_f32_16x16x32_bf16(
                        asbf(A[i]), bfr[(i * 4 + q) * 64 + lane], acc[q], 0, 0, 0);
            VMW(0);
            CANCHK(Bv, ok);
            tries = 0;
            while (!ok && ++tries < MAX_RETRY) {
                GLD16_ISSUE(Bv, vb); VMW(0); CANCHK(Bv, ok);
            }
#pragma unroll
            for (int i = 0; i < 16; ++i)
#pragma unroll
                for (int q = 0; q < 4; ++q)
                    acc[q] = __builtin_amdgcn_mfma_f32_16x16x32_bf16(
                        asbf(Bv[i]), bfr[hbase + (i * 4 + q) * 64 + lane], acc[q], 0, 0, 0);
        }

        // ---- epilogue: fire-and-forget stores (no drain, no publish) ----
        unsigned short* hw = ((layer == 0) ? h0b : h1b) + (size_t)(t + 1) * SLOT_ELEMS;
        float hv[4];
#pragma unroll
        for (int r = 0; r < 4; ++r) {
            int row = row0 + quad * 4 + r;
            float ig = sigm(acc[0][r]);
            float fg = sigm(acc[1][r]);
            float gg = tanhv(acc[2][r]);
            float og = sigm(acc[3][r]);
            float cy = c[r] * fg + ig * gg;
            float hy = og * tanhv(cy);
            c[r] = cy;
            hv[r] = hy;
            stg_coh(hw + row * Hn + colh, f2bf(hy));
        }
        if (layer == 1) {
#pragma unroll
            for (int r = 0; r < 4; ++r) {
                int row = row0 + quad * 4 + r;
                out[(size_t)row * (Tn * Hn) + (size_t)t * Hn + colh] = hv[r];
            }
        }
        if (t == Tn - 1) {
#pragma unroll
            for (int r = 0; r < 4; ++r) {
                int row = row0 + quad * 4 + r;
                out[OUT_HT + layer * (Bn * Hn) + row * Hn + colh] = hv[r];
                out[OUT_CT + layer * (Bn * Hn) + row * Hn + colh] = c[r];
            }
        }
    }
}

// =================== flags-mode kernel (v5 verbatim) ===================
__launch_bounds__(256, 1)
__global__ void lstm_flags(const float* __restrict__ x,
                           const float* __restrict__ wxh0, const float* __restrict__ whh0,
                           const float* __restrict__ wxh1, const float* __restrict__ whh1,
                           const float* __restrict__ bx0, const float* __restrict__ bh0,
                           const float* __restrict__ bx1, const float* __restrict__ bh1,
                           float* __restrict__ out,
                           unsigned short* __restrict__ h0b,
                           unsigned short* __restrict__ h1b,
                           int* __restrict__ done, int nslot) {
    extern __shared__ char smem[];
    const int layer = blockIdx.x >> 5;
    const int cb    = blockIdx.x & 31;
    const int wv    = threadIdx.x >> 6;
    const int lane  = threadIdx.x & 63;
    const int quad  = lane >> 4;
    const int ln    = lane & 15;
    const int row0  = wv << 4;
    const int colh  = (cb << 4) + ln;

    STAGE_WEIGHTS();

    float bias[4];
#pragma unroll
    for (int q = 0; q < 4; ++q) {
        int gc = q * Hn + colh;
        bias[q] = (layer == 0) ? (bx0[gc] + bh0[gc]) : (bx1[gc] + bh1[gc]);
    }

    const float* xrow0 = x + (size_t)(row0 + ln) * Tn * In + quad * 8;
    const int hoff = (row0 + ln) * Hn + quad * 8;

    const int lm = lane & 31;
    const int* d0 = done + ((0 * 4 + wv) * Tn) * 32 + lm;
    const int* d1 = done + ((1 * 4 + wv) * Tn) * 32 + lm;
    int* pub = done + ((layer * 4 + wv) * Tn) * 32 + cb;

    float c[4] = {0.f, 0.f, 0.f, 0.f};
    int rs = 0, wsl = 1;
    int gdone = -1;

    for (int t = 0; t < Tn; ++t) {
        f32x4 acc[4];
#pragma unroll
        for (int q = 0; q < 4; ++q) acc[q] = (f32x4){bias[q], bias[q], bias[q], bias[q]};

        if (layer == 0) {
            const float* xp = xrow0 + (size_t)t * In;
            f32x4 xr[16];
#pragma unroll
            for (int i = 0; i < 8; ++i) {
                xr[2 * i]     = *(const f32x4*)(xp + i * 32);
                xr[2 * i + 1] = *(const f32x4*)(xp + i * 32 + 4);
            }
            bf16x8 axc[8];
#pragma unroll
            for (int i = 0; i < 8; ++i) {
                f32x4 xa = xr[2 * i], xc = xr[2 * i + 1];
                axc[i][0] = (short)f2bf(xa[0]); axc[i][1] = (short)f2bf(xa[1]);
                axc[i][2] = (short)f2bf(xa[2]); axc[i][3] = (short)f2bf(xa[3]);
                axc[i][4] = (short)f2bf(xc[0]); axc[i][5] = (short)f2bf(xc[1]);
                axc[i][6] = (short)f2bf(xc[2]); axc[i][7] = (short)f2bf(xc[3]);
            }
#pragma unroll
            for (int i = 0; i < 8; ++i)
#pragma unroll
                for (int q = 0; q < 4; ++q)
                    acc[q] = __builtin_amdgcn_mfma_f32_16x16x32_bf16(
                        axc[i], bfr[(i * 4 + q) * 64 + lane], acc[q], 0, 0, 0);

            {
                int g = t + 1 - nslot;
                if (g >= 0 && g > gdone) {
                    int probe = g + 32; if (probe > Tn - 1) probe = Tn - 1;
                    if (__all(ld_cnt(d1 + probe * 32) > 0)) gdone = probe;
                    else {
                        const int* gp = d1 + g * 32;
                        while (!__all(ld_cnt(gp) > 0)) __builtin_amdgcn_s_sleep(4);
                        gdone = g;
                    }
                }
            }
            if (t > 0) {
                const int* p = d0 + (t - 1) * 32;
                while (!__all(ld_cnt(p) > 0)) { }
            }
            asm volatile("" ::: "memory");

            const unsigned short* hp = h0b + (size_t)rs * SLOT_ELEMS + hoff;
            f32x4 A[16];
            uint64_t va = (uint64_t)hp;
            GLD16_ISSUE(A, va);
            VMW(12);
#pragma unroll
            for (int i = 0; i < 4; ++i)
#pragma unroll
                for (int q = 0; q < 4; ++q)
                    acc[q] = __builtin_amdgcn_mfma_f32_16x16x32_bf16(
                        asbf(A[i]), bfr[hbase + (i * 4 + q) * 64 + lane], acc[q], 0, 0, 0);
            VMW(8);
#pragma unroll
            for (int i = 4; i < 8; ++i)
#pragma unroll
                for (int q = 0; q < 4; ++q)
                    acc[q] = __builtin_amdgcn_mfma_f32_16x16x32_bf16(
                        asbf(A[i]), bfr[hbase + (i * 4 + q) * 64 + lane], acc[q], 0, 0, 0);
            VMW(4);
#pragma unroll
            for (int i = 8; i < 12; ++i)
#pragma unroll
                for (int q = 0; q < 4; ++q)
                    acc[q] = __builtin_amdgcn_mfma_f32_16x16x32_bf16(
                        asbf(A[i]), bfr[hbase + (i * 4 + q) * 64 + lane], acc[q], 0, 0, 0);
            VMW(0);
#pragma unroll
            for (int i = 12; i < 16; ++i)
#pragma unroll
                for (int q = 0; q < 4; ++q)
                    acc[q] = __builtin_amdgcn_mfma_f32_16x16x32_bf16(
                        asbf(A[i]), bfr[hbase + (i * 4 + q) * 64 + lane], acc[q], 0, 0, 0);
        } else {
            {
                const int* p = d0 + t * 32;
                while (!__all(ld_cnt(p) > 0)) { }
            }
            asm volatile("" ::: "memory");
            const unsigned short* p0 = h0b + (size_t)wsl * SLOT_ELEMS + hoff;
            f32x4 A[16], Bv[16];
            uint64_t va = (uint64_t)p0;
            GLD16_ISSUE(A, va);
            if (t > 0) {
                const int* p = d1 + (t - 1) * 32;
                while (!__all(ld_cnt(p) > 0)) { }
            }
            asm volatile("" ::: "memory");
            const unsigned short* p1 = h1b + (size_t)rs * SLOT_ELEMS + hoff;
            uint64_t vb = (uint64_t)p1;
            GLD16_ISSUE(Bv, vb);
            VMW(28);
#pragma unroll
            for (int i = 0; i < 4; ++i)
#pragma unroll
                for (int q = 0; q < 4; ++q)
                    acc[q] = __builtin_amdgcn_mfma_f32_16x16x32_bf16(
                        asbf(A[i]), bfr[(i * 4 + q) * 64 + lane], acc[q], 0, 0, 0);
            VMW(24);
#pragma unroll
            for (int i = 4; i < 8; ++i)
#pragma unroll
                for (int q = 0; q < 4; ++q)
                    acc[q] = __builtin_amdgcn_mfma_f32_16x16x32_bf16(
                        asbf(A[i]), bfr[(i * 4 + q) * 64 + lane], acc[q], 0, 0, 0);
            VMW(20);
#pragma unroll
            for (int i = 8; i < 12; ++i)
#pragma unroll
                for (int q = 0; q < 4; ++q)
                    acc[q] = __builtin_amdgcn_mfma_f32_16x16x32_bf16(
                        asbf(A[i]), bfr[(i * 4 + q) * 64 + lane], acc[q], 0, 0, 0);
            VMW(16);
#pragma unroll
            for (int i = 12; i < 16; ++i)
#pragma unroll
                for (int q = 0; q < 4; ++q)
                    acc[q] = __builtin_amdgcn_mfma_f32_16x16x32_bf16(
                        asbf(A[i]), bfr[(i * 4 + q) * 64 + lane], acc[q], 0, 0, 0);
            VMW(12);
#pragma unroll
            for (int i = 0; i < 4; ++i)
#pragma unroll
                for (int q = 0; q < 4; ++q)
                    acc[q] = __builtin_amdgcn_mfma_f32_16x16x32_bf16(
                        asbf(Bv[i]), bfr[hbase + (i * 4 + q) * 64 + lane], acc[q], 0, 0, 0);
            VMW(8);
#pragma unroll
            for (int i = 4; i < 8; ++i)
#pragma unroll
                for (int q = 0; q < 4; ++q)
                    acc[q] = __builtin_amdgcn_mfma_f32_16x16x32_bf16(
                        asbf(Bv[i]), bfr[hbase + (i * 4 + q) * 64 + lane], acc[q], 0, 0, 0);
            VMW(4);
#pragma unroll
            for (int i = 8; i < 12; ++i)
#pragma unroll
                for (int q = 0; q < 4; ++q)
                    acc[q] = __builtin_amdgcn_mfma_f32_16x16x32_bf16(
                        asbf(Bv[i]), bfr[hbase + (i * 4 + q) * 64 + lane], acc[q], 0, 0, 0);
            VMW(0);
#pragma unroll
            for (int i = 12; i < 16; ++i)
#pragma unroll
                for (int q = 0; q < 4; ++q)
                    acc[q] = __builtin_amdgcn_mfma_f32_16x16x32_bf16(
                        asbf(Bv[i]), bfr[hbase + (i * 4 + q) * 64 + lane], acc[q], 0, 0, 0);
        }

        unsigned short* hw = ((layer == 0) ? h0b : h1b) + (size_t)wsl * SLOT_ELEMS;
        float hv[4];
#pragma unroll
        for (int r = 0; r < 4; ++r) {
            int row = row0 + quad * 4 + r;
            float ig = sigm(acc[0][r]);
            float fg = sigm(acc[1][r]);
            float gg = tanhv(acc[2][r]);
            float og = sigm(acc[3][r]);
            float cy = c[r] * fg + ig * gg;
            float hy = og * tanhv(cy);
            c[r] = cy;
            hv[r] = hy;
            stg_coh(hw + row * Hn + colh, f2bf(hy));
        }
        asm volatile("s_waitcnt vmcnt(0)" ::: "memory");
        if (lane == 0) st_flag(pub + t * 32, t + 1);

        if (layer == 1) {
#pragma unroll
            for (int r = 0; r < 4; ++r) {
                int row = row0 + quad * 4 + r;
                out[(size_t)row * (Tn * Hn) + (size_t)t * Hn + colh] = hv[r];
            }
        }
        if (t == Tn - 1) {
#pragma unroll
            for (int r = 0; r < 4; ++r) {
                int row = row0 + quad * 4 + r;
                out[OUT_HT + layer * (Bn * Hn) + row * Hn + colh] = hv[r];
                out[OUT_CT + layer * (Bn * Hn) + row * Hn + colh] = c[r];
            }
        }

        rs = wsl;
        wsl = (wsl + 1 == nslot) ? 0 : wsl + 1;
    }
}

extern "C" void kernel_launch(void* const* d_in, const int* in_sizes, int n_in,
                              void* d_out, int out_size, void* d_ws, size_t ws_size,
                              hipStream_t stream) {
    const float* x    = (const float*)d_in[0];
    const float* wxh0 = (const float*)d_in[1];
    const float* bxh0 = (const float*)d_in[2];
    const float* whh0 = (const float*)d_in[3];
    const float* bhh0 = (const float*)d_in[4];
    const float* wxh1 = (const float*)d_in[5];
    const float* bxh1 = (const float*)d_in[6];
    const float* whh1 = (const float*)d_in[7];
    const float* bhh1 = (const float*)d_in[8];
    float* out = (float*)d_out;

    char* ws = (char*)d_ws;
    int* done = (int*)ws;
    unsigned short* h0b = (unsigned short*)(ws + DONE_BYTES);

    static int lds_attr_set = 0;
    if (!lds_attr_set) {
        hipFuncSetAttribute((const void*)lstm_canary,
                            hipFuncAttributeMaxDynamicSharedMemorySize, LDS_BYTES);
        hipFuncSetAttribute((const void*)lstm_flags,
                            hipFuncAttributeMaxDynamicSharedMemorySize, LDS_BYTES);
        lds_attr_set = 1;
    }

    const size_t need_can = (size_t)DONE_BYTES
                          + 2ull * NSLOT_CAN * SLOT_ELEMS * 2 + 64;
    if (ws_size >= need_can) {
        // canary mode: 513 slots per ring, no reuse, zero flags
        unsigned short* h1b = h0b + (size_t)NSLOT_CAN * SLOT_ELEMS;
        lstm_prep<<<dim3(1024), dim3(256), 0, stream>>>(
            (u64*)h0b, (u64*)h1b, done, 1);
        lstm_canary<<<dim3(NBLK), dim3(256), LDS_BYTES, stream>>>(
            x, wxh0, whh0, wxh1, whh1, bxh0, bhh0, bxh1, bhh1, out, h0b, h1b);
    } else {
        // flags mode (v5): elastic rings + done-vector signaling
        long nslot_l = (long)((ws_size - DONE_BYTES) / (2 * (size_t)SLOT_ELEMS * 2));
        int nslot = (int)(nslot_l < 3 ? 3 : (nslot_l > Tn + 1 ? Tn + 1 : nslot_l));
        unsigned short* h1b = h0b + (size_t)nslot * SLOT_ELEMS;
        lstm_prep<<<dim3(256), dim3(256), 0, stream>>>(
            (u64*)h0b, (u64*)h1b, done, 0);
        lstm_flags<<<dim3(NBLK), dim3(256), LDS_BYTES, stream>>>(
            x, wxh0, whh0, wxh1, whh1, bxh0, bhh0, bxh1, bhh1,
            out, h0b, h1b, done, nslot);
    }
}